// Round 1
// baseline (2021.186 us; speedup 1.0000x reference)
//
#include <hip/hip_runtime.h>

typedef __attribute__((ext_vector_type(8))) short short8;
typedef __attribute__((ext_vector_type(4))) float f32x4;

#define DEV static __device__ __forceinline__

DEV unsigned short f2bf(float x) {
  union { float f; unsigned int u; } c; c.f = x;
  unsigned int r = c.u + 0x7fffu + ((c.u >> 16) & 1u);
  return (unsigned short)(r >> 16);
}
DEV float bf2f(unsigned short s) {
  union { unsigned int u; float f; } c; c.u = ((unsigned int)s) << 16;
  return c.f;
}
DEV float elu1(float x) { return x > 0.f ? x + 1.f : __expf(x); }

DEV void gload_lds16(const void* g, void* l) {
  __builtin_amdgcn_global_load_lds(
      (const __attribute__((address_space(1))) unsigned int*)g,
      (__attribute__((address_space(3))) unsigned int*)l, 16, 0, 0);
}

// ---------------- weight transpose + bf16 convert: dst[layer][N][K] = src[layer][K][N]
__global__ __launch_bounds__(256)
void wprep(const float* __restrict__ src, unsigned short* __restrict__ dst,
           int K, int N, int dls) {
  const int layer = blockIdx.z;
  src += (size_t)layer * K * N;
  dst += (size_t)layer * dls;
  __shared__ float tile[64][65];
  const int n0 = blockIdx.x * 64, k0 = blockIdx.y * 64;
  const int c = threadIdx.x & 63, r4 = threadIdx.x >> 6;
#pragma unroll
  for (int i = 0; i < 16; ++i) {
    int r = (i << 2) + r4;
    tile[r][c] = src[(size_t)(k0 + r) * N + n0 + c];
  }
  __syncthreads();
#pragma unroll
  for (int i = 0; i < 16; ++i) {
    int r = (i << 2) + r4;
    dst[(size_t)(n0 + r) * K + k0 + c] = f2bf(tile[c][r]);
  }
}

// ---------------- f32 -> bf16 elementwise (x4)
__global__ __launch_bounds__(256)
void cvt_bf16(const float* __restrict__ src, unsigned short* __restrict__ dst, int n4) {
  int i = blockIdx.x * 256 + threadIdx.x;
  if (i >= n4) return;
  float4 v = ((const float4*)src)[i];
  ushort4 o;
  o.x = f2bf(v.x); o.y = f2bf(v.y); o.z = f2bf(v.z); o.w = f2bf(v.w);
  ((ushort4*)dst)[i] = o;
}

// ---------------- bf16 MFMA GEMM, BT input (B stored N x K), 128x128 tile, BK=64
// EPI: 0 = f32 store; 1 = relu -> bf16; 2 = f32 store with elu1 on cols<256; 3 = elu1 -> bf16
template<int EPI>
__global__ __launch_bounds__(256)
void gemm_bt(const unsigned short* __restrict__ A0,
             const unsigned short* __restrict__ A1,   // concat half (k>=256), stride 256; or null
             const unsigned short* __restrict__ BT,
             float* __restrict__ Cf, unsigned short* __restrict__ Cb,
             int M, int N, int K, int lda) {
  __shared__ __align__(16) unsigned short As[128 * 64];
  __shared__ __align__(16) unsigned short Bs[128 * 64];
  const int tid = threadIdx.x;
  const int lane = tid & 63, wave = tid >> 6;
  const int tn = N >> 7;
  const int bm = (int)blockIdx.x / tn, bn = (int)blockIdx.x % tn;
  const int wm = (wave >> 1) << 6, wn = (wave & 1) << 6;
  const int lr = lane & 15, lk = lane >> 4;

  f32x4 acc[4][4];
#pragma unroll
  for (int i = 0; i < 4; ++i)
#pragma unroll
    for (int j = 0; j < 4; ++j) acc[i][j] = (f32x4){0.f, 0.f, 0.f, 0.f};

  for (int k0 = 0; k0 < K; k0 += 64) {
#pragma unroll
    for (int i = 0; i < 4; ++i) {
      const int cb = (i << 2) + wave;            // chunk group (64 chunks of 16B each)
      const int id = (cb << 6) + lane;           // 0..1023
      const int row = id >> 3, ck = id & 7;
      const int gk = k0 + ((ck ^ (row & 7)) << 3);  // XOR-swizzled source chunk
      const unsigned short* srcA;
      if (A1) {
        srcA = (gk < 256) ? (A0 + (size_t)(bm * 128 + row) * 256 + gk)
                          : (A1 + (size_t)(bm * 128 + row) * 256 + (gk - 256));
      } else {
        srcA = A0 + (size_t)(bm * 128 + row) * lda + gk;
      }
      gload_lds16(srcA, As + (size_t)cb * 512);
      const unsigned short* srcB = BT + (size_t)(bn * 128 + row) * K + gk;
      gload_lds16(srcB, Bs + (size_t)cb * 512);
    }
    __syncthreads();
#pragma unroll
    for (int kk = 0; kk < 2; ++kk) {
      short8 af[4], bfr[4];
#pragma unroll
      for (int mi = 0; mi < 4; ++mi) {
        const int row = wm + mi * 16 + lr;
        const int ck = ((kk << 2) + lk) ^ (row & 7);
        af[mi] = *(const short8*)(As + row * 64 + ck * 8);
      }
#pragma unroll
      for (int ni = 0; ni < 4; ++ni) {
        const int row = wn + ni * 16 + lr;
        const int ck = ((kk << 2) + lk) ^ (row & 7);
        bfr[ni] = *(const short8*)(Bs + row * 64 + ck * 8);
      }
#pragma unroll
      for (int mi = 0; mi < 4; ++mi)
#pragma unroll
        for (int ni = 0; ni < 4; ++ni)
          acc[mi][ni] = __builtin_amdgcn_mfma_f32_16x16x32_bf16(af[mi], bfr[ni], acc[mi][ni], 0, 0, 0);
    }
    __syncthreads();
  }

  const int cr = lk << 2;
#pragma unroll
  for (int mi = 0; mi < 4; ++mi) {
#pragma unroll
    for (int ni = 0; ni < 4; ++ni) {
      const int colbase = bn * 128 + wn + ni * 16;
      const bool kside = colbase < 256;
#pragma unroll
      for (int j = 0; j < 4; ++j) {
        const int row = bm * 128 + wm + mi * 16 + cr + j;
        const int col = colbase + lr;
        float v = acc[mi][ni][j];
        if (EPI == 0) {
          Cf[(size_t)row * N + col] = v;
        } else if (EPI == 1) {
          Cb[(size_t)row * N + col] = f2bf(fmaxf(v, 0.f));
        } else if (EPI == 2) {
          Cf[(size_t)row * N + col] = kside ? elu1(v) : v;
        } else {
          Cb[(size_t)row * N + col] = f2bf(elu1(v));
        }
      }
    }
  }
}

// ---------------- KV partial reduction: KV[d][v] = sum_s K[s][d]*V[s][v]; Ksum[d] = sum_s K[s][d]
// kv layout: [n*4800+s][512], cols 0..255 = K (elu already applied), 256..511 = V
// grid (10 chunks, 8 heads, 4 batch), 256 threads; each wave owns 120 s-rows.
__global__ __launch_bounds__(256)
void kv_partial(const float* __restrict__ kv, float* __restrict__ part) {
  const int ch = blockIdx.x, h = blockIdx.y, n = blockIdx.z;
  const int t = threadIdx.x, wave = t >> 6, lane = t & 63;
  __shared__ float kb[4][8][32];
  __shared__ float vb[4][8][32];
  const int dq = lane >> 3, vq = lane & 7;
  float a[4][4];
  float ks[4] = {0.f, 0.f, 0.f, 0.f};
#pragma unroll
  for (int i = 0; i < 4; ++i)
#pragma unroll
    for (int j = 0; j < 4; ++j) a[i][j] = 0.f;

  const int s_base = ch * 480 + wave * 120;
  for (int it = 0; it < 15; ++it) {
    __syncthreads();
#pragma unroll
    for (int i = 0; i < 2; ++i) {
      int f = i * 64 + lane;
      int r = f >> 4, c4 = f & 15;
      const float* gp = kv + ((size_t)(n * 4800 + s_base + it * 8 + r)) * 512 +
                        (c4 < 8 ? h * 32 + c4 * 4 : 256 + h * 32 + (c4 - 8) * 4);
      float4 val = *(const float4*)gp;
      if (c4 < 8) *(float4*)&kb[wave][r][c4 * 4] = val;
      else        *(float4*)&vb[wave][r][(c4 - 8) * 4] = val;
    }
    __syncthreads();
#pragma unroll
    for (int si = 0; si < 8; ++si) {
      float4 kq = *(const float4*)&kb[wave][si][dq * 4];
      float4 vv = *(const float4*)&vb[wave][si][vq * 4];
      ks[0] += kq.x; ks[1] += kq.y; ks[2] += kq.z; ks[3] += kq.w;
      a[0][0] += kq.x * vv.x; a[0][1] += kq.x * vv.y; a[0][2] += kq.x * vv.z; a[0][3] += kq.x * vv.w;
      a[1][0] += kq.y * vv.x; a[1][1] += kq.y * vv.y; a[1][2] += kq.y * vv.z; a[1][3] += kq.y * vv.w;
      a[2][0] += kq.z * vv.x; a[2][1] += kq.z * vv.y; a[2][2] += kq.z * vv.z; a[2][3] += kq.z * vv.w;
      a[3][0] += kq.w * vv.x; a[3][1] += kq.w * vv.y; a[3][2] += kq.w * vv.z; a[3][3] += kq.w * vv.w;
    }
  }
  float* pb = part + ((size_t)((n * 8 + h) * 40 + ch * 4 + wave)) * 1056;
#pragma unroll
  for (int i = 0; i < 4; ++i) {
#pragma unroll
    for (int j = 0; j < 4; ++j) pb[(dq * 4 + i) * 32 + vq * 4 + j] = a[i][j];
    if (vq == 0) pb[1024 + dq * 4 + i] = ks[i];
  }
}

// ---------------- reduce 40 partials; KV written bf16 in exact MFMA B-fragment order
__global__ __launch_bounds__(256)
void kv_reduce(const float* __restrict__ part, unsigned short* __restrict__ KVb,
               float* __restrict__ Ksum) {
  const int nh = blockIdx.x, t = threadIdx.x;
  const float* pb = part + (size_t)nh * 40 * 1056;
#pragma unroll
  for (int j = 0; j < 4; ++j) {
    int e = t * 4 + j;
    float s = 0.f;
    for (int c = 0; c < 40; ++c) s += pb[c * 1056 + e];
    int dd = e >> 5, vv = e & 31;
    size_t addr = ((size_t)(nh * 2 + (vv >> 4)) * 64 + ((dd >> 3) * 16 + (vv & 15))) * 8 + (dd & 7);
    KVb[addr] = f2bf(s);
  }
  if (t < 32) {
    float s = 0.f;
    for (int c = 0; c < 40; ++c) s += pb[c * 1056 + 1024 + t];
    Ksum[nh * 32 + t] = s;
  }
}

// ---------------- msg = (Q @ KV) * z, z = 1/(Q.Ksum + 1e-6); Q already elu'd, bf16
__global__ __launch_bounds__(256)
void msg_kernel(const unsigned short* __restrict__ qb, const unsigned short* __restrict__ KVb,
                const float* __restrict__ Ksum, unsigned short* __restrict__ msg) {
  const int n = blockIdx.y;
  const int wave = threadIdx.x >> 6, lane = threadIdx.x & 63;
  const int lr = lane & 15, lk = lane >> 4;
  const int lrow = blockIdx.x * 64 + wave * 16 + lr;
  const unsigned short* qrow = qb + ((size_t)n * 4800 + lrow) * 256;
  const short8* kvv = (const short8*)KVb;
  for (int h = 0; h < 8; ++h) {
    short8 af = *(const short8*)(qrow + h * 32 + lk * 8);
    const float* ksp = Ksum + (n * 8 + h) * 32 + lk * 8;
    float zp = 0.f;
#pragma unroll
    for (int j = 0; j < 8; ++j) zp += bf2f((unsigned short)af[j]) * ksp[j];
    zp += __shfl_xor(zp, 16);
    zp += __shfl_xor(zp, 32);
    float z = 1.f / (zp + 1e-6f);
    short8 b0 = kvv[((size_t)(n * 8 + h) * 2 + 0) * 64 + lane];
    short8 b1 = kvv[((size_t)(n * 8 + h) * 2 + 1) * 64 + lane];
    f32x4 acc0 = (f32x4){0.f, 0.f, 0.f, 0.f}, acc1 = (f32x4){0.f, 0.f, 0.f, 0.f};
    acc0 = __builtin_amdgcn_mfma_f32_16x16x32_bf16(af, b0, acc0, 0, 0, 0);
    acc1 = __builtin_amdgcn_mfma_f32_16x16x32_bf16(af, b1, acc1, 0, 0, 0);
#pragma unroll
    for (int j = 0; j < 4; ++j) {
      int rr = lk * 4 + j;
      float zj = __shfl(z, rr);
      int row = blockIdx.x * 64 + wave * 16 + rr;
      size_t base = ((size_t)n * 4800 + row) * 256 + h * 32;
      msg[base + lr] = f2bf(acc0[j] * zj);
      msg[base + 16 + lr] = f2bf(acc1[j] * zj);
    }
  }
}

// ---------------- LayerNorm over C=256; MODE 0: bf16 out; MODE 1: out = x + LN(in), f32 + bf16
template<int MODE>
__global__ __launch_bounds__(256)
void ln_kernel(const float* __restrict__ in, const float* __restrict__ xres,
               const float* __restrict__ w, const float* __restrict__ b,
               float* __restrict__ outf, unsigned short* __restrict__ outb) {
  const int wave = threadIdx.x >> 6, lane = threadIdx.x & 63;
  const size_t row = (size_t)blockIdx.x * 4 + wave;
  const float4 xv = ((const float4*)(in + row * 256))[lane];
  float s = xv.x + xv.y + xv.z + xv.w;
#pragma unroll
  for (int o = 1; o < 64; o <<= 1) s += __shfl_xor(s, o);
  const float mu = s * (1.f / 256.f);
  float d0 = xv.x - mu, d1 = xv.y - mu, d2 = xv.z - mu, d3 = xv.w - mu;
  float vs = d0 * d0 + d1 * d1 + d2 * d2 + d3 * d3;
#pragma unroll
  for (int o = 1; o < 64; o <<= 1) vs += __shfl_xor(vs, o);
  const float rstd = rsqrtf(vs * (1.f / 256.f) + 1e-5f);
  const float4 wv = ((const float4*)w)[lane];
  const float4 bv = ((const float4*)b)[lane];
  float y0 = d0 * rstd * wv.x + bv.x;
  float y1 = d1 * rstd * wv.y + bv.y;
  float y2 = d2 * rstd * wv.z + bv.z;
  float y3 = d3 * rstd * wv.w + bv.w;
  if (MODE == 0) {
    ushort4 o; o.x = f2bf(y0); o.y = f2bf(y1); o.z = f2bf(y2); o.w = f2bf(y3);
    ((ushort4*)(outb + row * 256))[lane] = o;
  } else {
    const float4 xr = ((const float4*)(xres + row * 256))[lane];
    float o0 = xr.x + y0, o1 = xr.y + y1, o2 = xr.z + y2, o3 = xr.w + y3;
    ((float4*)(outf + row * 256))[lane] = make_float4(o0, o1, o2, o3);
    ushort4 ob; ob.x = f2bf(o0); ob.y = f2bf(o1); ob.z = f2bf(o2); ob.w = f2bf(o3);
    ((ushort4*)(outb + row * 256))[lane] = ob;
  }
}

extern "C" void kernel_launch(void* const* d_in, const int* in_sizes, int n_in,
                              void* d_out, int out_size, void* d_ws, size_t ws_size,
                              hipStream_t stream) {
  (void)in_sizes; (void)n_in; (void)out_size; (void)ws_size;
  const float* feat0 = (const float*)d_in[0];
  const float* feat1 = (const float*)d_in[1];
  const float* Wq = (const float*)d_in[2];
  const float* Wk = (const float*)d_in[3];
  const float* Wv = (const float*)d_in[4];
  const float* Wm = (const float*)d_in[5];
  const float* W1 = (const float*)d_in[6];
  const float* W2 = (const float*)d_in[7];
  const float* ln1w = (const float*)d_in[8];
  const float* ln1b = (const float*)d_in[9];
  const float* ln2w = (const float*)d_in[10];
  const float* ln2b = (const float*)d_in[11];

  float* F0 = (float*)d_out;
  float* F1 = F0 + (size_t)4915200;

  size_t off = 0;
  auto alloc = [&](size_t bytes) -> void* {
    void* p = (char*)d_ws + off;
    off += (bytes + 255) & ~(size_t)255;
    return p;
  };
  unsigned short* qb     = (unsigned short*)alloc((size_t)19200 * 256 * 2);
  float*          kvbuf  = (float*)alloc((size_t)19200 * 512 * 4);
  unsigned short* msgb   = (unsigned short*)alloc((size_t)19200 * 256 * 2);
  unsigned short* msglnb = (unsigned short*)alloc((size_t)19200 * 256 * 2);
  unsigned short* F0b    = (unsigned short*)alloc((size_t)19200 * 256 * 2);
  unsigned short* F1b    = (unsigned short*)alloc((size_t)19200 * 256 * 2);
  float*          part   = (float*)alloc((size_t)32 * 40 * 1056 * 4);
  unsigned short* KVb    = (unsigned short*)alloc((size_t)32768 * 2);
  float*          Ksum   = (float*)alloc((size_t)1024 * 4);
  unsigned short* WqT    = (unsigned short*)alloc((size_t)8 * 65536 * 2);
  unsigned short* WkvT   = (unsigned short*)alloc((size_t)8 * 131072 * 2);
  unsigned short* WmT    = (unsigned short*)alloc((size_t)8 * 65536 * 2);
  unsigned short* W1T    = (unsigned short*)alloc((size_t)8 * 262144 * 2);
  unsigned short* W2T    = (unsigned short*)alloc((size_t)8 * 131072 * 2);
  float* mm = kvbuf;                                            // reuse: first half
  float* tt = kvbuf;                                            // reuse: first half
  unsigned short* h1b = (unsigned short*)(kvbuf + (size_t)19200 * 256);  // second half

  hipMemcpyAsync(F0, feat0, (size_t)4915200 * 4, hipMemcpyDeviceToDevice, stream);
  hipMemcpyAsync(F1, feat1, (size_t)4915200 * 4, hipMemcpyDeviceToDevice, stream);
  cvt_bf16<<<4800, 256, 0, stream>>>(feat0, F0b, 1228800);
  cvt_bf16<<<4800, 256, 0, stream>>>(feat1, F1b, 1228800);

  wprep<<<dim3(4, 4, 8), 256, 0, stream>>>(Wq, WqT, 256, 256, 65536);
  wprep<<<dim3(4, 4, 8), 256, 0, stream>>>(Wk, WkvT, 256, 256, 131072);
  wprep<<<dim3(4, 4, 8), 256, 0, stream>>>(Wv, WkvT + 65536, 256, 256, 131072);
  wprep<<<dim3(4, 4, 8), 256, 0, stream>>>(Wm, WmT, 256, 256, 65536);
  wprep<<<dim3(8, 8, 8), 256, 0, stream>>>(W1, W1T, 512, 512, 262144);
  wprep<<<dim3(4, 8, 8), 256, 0, stream>>>(W2, W2T, 512, 256, 131072);

  auto enc = [&](float* X, unsigned short* Xb, unsigned short* Sb, int i) {
    gemm_bt<3><<<300, 256, 0, stream>>>(Xb, nullptr, WqT + (size_t)i * 65536, nullptr, qb, 19200, 256, 256, 256);
    gemm_bt<2><<<600, 256, 0, stream>>>(Sb, nullptr, WkvT + (size_t)i * 131072, kvbuf, nullptr, 19200, 512, 256, 256);
    kv_partial<<<dim3(10, 8, 4), 256, 0, stream>>>(kvbuf, part);
    kv_reduce<<<32, 256, 0, stream>>>(part, KVb, Ksum);
    msg_kernel<<<dim3(75, 4), 256, 0, stream>>>(qb, KVb, Ksum, msgb);
    gemm_bt<0><<<300, 256, 0, stream>>>(msgb, nullptr, WmT + (size_t)i * 65536, mm, nullptr, 19200, 256, 256, 256);
    ln_kernel<0><<<4800, 256, 0, stream>>>(mm, nullptr, ln1w + i * 256, ln1b + i * 256, nullptr, msglnb);
    gemm_bt<1><<<600, 256, 0, stream>>>(Xb, msglnb, W1T + (size_t)i * 262144, nullptr, h1b, 19200, 512, 512, 256);
    gemm_bt<0><<<300, 256, 0, stream>>>(h1b, nullptr, W2T + (size_t)i * 131072, tt, nullptr, 19200, 256, 512, 512);
    ln_kernel<1><<<4800, 256, 0, stream>>>(tt, X, ln2w + i * 256, ln2b + i * 256, X, Xb);
  };

  for (int i = 0; i < 8; ++i) {
    if ((i & 1) == 0) { enc(F0, F0b, F0b, i); enc(F1, F1b, F1b, i); }
    else              { enc(F0, F0b, F1b, i); enc(F1, F1b, F0b, i); }
  }
}

// Round 2
// 1626.911 us; speedup vs baseline: 1.2423x; 1.2423x over previous
//
#include <hip/hip_runtime.h>

typedef __attribute__((ext_vector_type(8))) short short8;
typedef __attribute__((ext_vector_type(4))) float f32x4;

#define DEV static __device__ __forceinline__

DEV unsigned short f2bf(float x) {
  union { float f; unsigned int u; } c; c.f = x;
  unsigned int r = c.u + 0x7fffu + ((c.u >> 16) & 1u);
  return (unsigned short)(r >> 16);
}
DEV float bf2f(unsigned short s) {
  union { unsigned int u; float f; } c; c.u = ((unsigned int)s) << 16;
  return c.f;
}
DEV float elu1(float x) { return x > 0.f ? x + 1.f : __expf(x); }

DEV void gload_lds16(const void* g, void* l) {
  __builtin_amdgcn_global_load_lds(
      (const __attribute__((address_space(1))) unsigned int*)g,
      (__attribute__((address_space(3))) unsigned int*)l, 16, 0, 0);
}

// ---------------- weight transpose + bf16 convert: dst[layer][N][K] = src[layer][K][N]
__global__ __launch_bounds__(256)
void wprep(const float* __restrict__ src, unsigned short* __restrict__ dst,
           int K, int N, int dls) {
  const int layer = blockIdx.z;
  src += (size_t)layer * K * N;
  dst += (size_t)layer * dls;
  __shared__ float tile[64][65];
  const int n0 = blockIdx.x * 64, k0 = blockIdx.y * 64;
  const int c = threadIdx.x & 63, r4 = threadIdx.x >> 6;
#pragma unroll
  for (int i = 0; i < 16; ++i) {
    int r = (i << 2) + r4;
    tile[r][c] = src[(size_t)(k0 + r) * N + n0 + c];
  }
  __syncthreads();
#pragma unroll
  for (int i = 0; i < 16; ++i) {
    int r = (i << 2) + r4;
    dst[(size_t)(n0 + r) * K + k0 + c] = f2bf(tile[c][r]);
  }
}

// ---------------- init: f32 copy + bf16 mirror
__global__ __launch_bounds__(256)
void init_feat(const float* __restrict__ src, float* __restrict__ dstf,
               unsigned short* __restrict__ dstb, int n4) {
  int i = blockIdx.x * 256 + threadIdx.x;
  if (i >= n4) return;
  float4 v = ((const float4*)src)[i];
  ((float4*)dstf)[i] = v;
  ushort4 o;
  o.x = f2bf(v.x); o.y = f2bf(v.y); o.z = f2bf(v.z); o.w = f2bf(v.w);
  ((ushort4*)dstb)[i] = o;
}

// ---------------- bf16 MFMA GEMM, BT input (B stored N x K), 128x128 tile, BK=64
// EPI: 1 = relu->bf16 (stride N); 2 = elu on col<256 ->bf16 (stride N);
//      3 = elu->bf16 (stride 256); 4 = merged qkv: q->Cb (stride 256, elu),
//          k/v->Cb2 (stride 512, elu on col<512)
template<int EPI>
__global__ __launch_bounds__(256)
void gemm_bt(const unsigned short* __restrict__ A0,
             const unsigned short* __restrict__ A1,   // concat half (k>=256), stride 256; or null
             const unsigned short* __restrict__ BT,
             unsigned short* __restrict__ Cb, unsigned short* __restrict__ Cb2,
             int M, int N, int K, int lda) {
  __shared__ __align__(16) unsigned short As[128 * 64];
  __shared__ __align__(16) unsigned short Bs[128 * 64];
  const int tid = threadIdx.x;
  const int lane = tid & 63, wave = tid >> 6;
  const int tn = N >> 7;
  const int bm = (int)blockIdx.x / tn, bn = (int)blockIdx.x % tn;
  const int wm = (wave >> 1) << 6, wn = (wave & 1) << 6;
  const int lr = lane & 15, lk = lane >> 4;

  f32x4 acc[4][4];
#pragma unroll
  for (int i = 0; i < 4; ++i)
#pragma unroll
    for (int j = 0; j < 4; ++j) acc[i][j] = (f32x4){0.f, 0.f, 0.f, 0.f};

  for (int k0 = 0; k0 < K; k0 += 64) {
#pragma unroll
    for (int i = 0; i < 4; ++i) {
      const int cb = (i << 2) + wave;
      const int id = (cb << 6) + lane;
      const int row = id >> 3, ck = id & 7;
      const int gk = k0 + ((ck ^ (row & 7)) << 3);
      const unsigned short* srcA;
      if (A1) {
        srcA = (gk < 256) ? (A0 + (size_t)(bm * 128 + row) * 256 + gk)
                          : (A1 + (size_t)(bm * 128 + row) * 256 + (gk - 256));
      } else {
        srcA = A0 + (size_t)(bm * 128 + row) * lda + gk;
      }
      gload_lds16(srcA, As + (size_t)cb * 512);
      const unsigned short* srcB = BT + (size_t)(bn * 128 + row) * K + gk;
      gload_lds16(srcB, Bs + (size_t)cb * 512);
    }
    __syncthreads();
#pragma unroll
    for (int kk = 0; kk < 2; ++kk) {
      short8 af[4], bfr[4];
#pragma unroll
      for (int mi = 0; mi < 4; ++mi) {
        const int row = wm + mi * 16 + lr;
        const int ck = ((kk << 2) + lk) ^ (row & 7);
        af[mi] = *(const short8*)(As + row * 64 + ck * 8);
      }
#pragma unroll
      for (int ni = 0; ni < 4; ++ni) {
        const int row = wn + ni * 16 + lr;
        const int ck = ((kk << 2) + lk) ^ (row & 7);
        bfr[ni] = *(const short8*)(Bs + row * 64 + ck * 8);
      }
#pragma unroll
      for (int mi = 0; mi < 4; ++mi)
#pragma unroll
        for (int ni = 0; ni < 4; ++ni)
          acc[mi][ni] = __builtin_amdgcn_mfma_f32_16x16x32_bf16(af[mi], bfr[ni], acc[mi][ni], 0, 0, 0);
    }
    __syncthreads();
  }

  const int cr = lk << 2;
#pragma unroll
  for (int mi = 0; mi < 4; ++mi) {
#pragma unroll
    for (int ni = 0; ni < 4; ++ni) {
      const int colbase = bn * 128 + wn + ni * 16;
#pragma unroll
      for (int j = 0; j < 4; ++j) {
        const int row = bm * 128 + wm + mi * 16 + cr + j;
        const int col = colbase + lr;
        float v = acc[mi][ni][j];
        if (EPI == 1) {
          Cb[(size_t)row * N + col] = f2bf(fmaxf(v, 0.f));
        } else if (EPI == 2) {
          Cb[(size_t)row * N + col] = f2bf(colbase < 256 ? elu1(v) : v);
        } else if (EPI == 3) {
          Cb[(size_t)row * 256 + col] = f2bf(elu1(v));
        } else {  // 4
          if (colbase < 256) Cb[(size_t)row * 256 + col] = f2bf(elu1(v));
          else Cb2[(size_t)row * 512 + (col - 256)] = f2bf(colbase < 512 ? elu1(v) : v);
        }
      }
    }
  }
}

// ---------------- fused GEMM (N=256 exactly) + LayerNorm epilogue.
// BM=128, BN=256, 8 waves (512 thr). EPI 0: LN -> bf16; EPI 1: residual + LN -> f32 + bf16
template<int EPI>
__global__ __launch_bounds__(512)
void gemm_ln(const unsigned short* __restrict__ A, const unsigned short* __restrict__ BT,
             const float* __restrict__ lnw, const float* __restrict__ lnb,
             const float* __restrict__ xres, float* __restrict__ outf,
             unsigned short* __restrict__ outb, int K) {
  __shared__ __align__(16) unsigned short As[128 * 64];
  __shared__ __align__(16) unsigned short Bs[256 * 64];
  const int tid = threadIdx.x;
  const int lane = tid & 63, wid = tid >> 6;
  const int bm = blockIdx.x;
  const int wm = (wid >> 2) << 6, wn = (wid & 3) << 6;
  const int lr = lane & 15, lk = lane >> 4;

  f32x4 acc[4][4];
#pragma unroll
  for (int i = 0; i < 4; ++i)
#pragma unroll
    for (int j = 0; j < 4; ++j) acc[i][j] = (f32x4){0.f, 0.f, 0.f, 0.f};

  for (int k0 = 0; k0 < K; k0 += 64) {
#pragma unroll
    for (int i = 0; i < 2; ++i) {
      const int cb = i * 8 + wid;
      const int id = (cb << 6) + lane;
      const int row = id >> 3, ck = id & 7;
      const int gk = k0 + ((ck ^ (row & 7)) << 3);
      gload_lds16(A + (size_t)(bm * 128 + row) * K + gk, As + (size_t)cb * 512);
    }
#pragma unroll
    for (int i = 0; i < 4; ++i) {
      const int cb = i * 8 + wid;
      const int id = (cb << 6) + lane;
      const int row = id >> 3, ck = id & 7;
      const int gk = k0 + ((ck ^ (row & 7)) << 3);
      gload_lds16(BT + (size_t)row * K + gk, Bs + (size_t)cb * 512);
    }
    __syncthreads();
#pragma unroll
    for (int kk = 0; kk < 2; ++kk) {
      short8 af[4], bfr[4];
#pragma unroll
      for (int mi = 0; mi < 4; ++mi) {
        const int row = wm + mi * 16 + lr;
        const int ck = ((kk << 2) + lk) ^ (row & 7);
        af[mi] = *(const short8*)(As + row * 64 + ck * 8);
      }
#pragma unroll
      for (int ni = 0; ni < 4; ++ni) {
        const int row = wn + ni * 16 + lr;
        const int ck = ((kk << 2) + lk) ^ (row & 7);
        bfr[ni] = *(const short8*)(Bs + row * 64 + ck * 8);
      }
#pragma unroll
      for (int mi = 0; mi < 4; ++mi)
#pragma unroll
        for (int ni = 0; ni < 4; ++ni)
          acc[mi][ni] = __builtin_amdgcn_mfma_f32_16x16x32_bf16(af[mi], bfr[ni], acc[mi][ni], 0, 0, 0);
    }
    __syncthreads();
  }

  // ---- cross-wave LN reduce (rows complete within block; 4 wn-groups per row)
  float* red = (float*)As;  // [128][8]: per row, 4 x (sum, sumsq)
  float wv[4], bv[4];
#pragma unroll
  for (int ni = 0; ni < 4; ++ni) {
    wv[ni] = lnw[wn + ni * 16 + lr];
    bv[ni] = lnb[wn + ni * 16 + lr];
  }
#pragma unroll
  for (int mi = 0; mi < 4; ++mi) {
#pragma unroll
    for (int j = 0; j < 4; ++j) {
      float s = 0.f, q = 0.f;
#pragma unroll
      for (int ni = 0; ni < 4; ++ni) {
        float v = acc[mi][ni][j];
        s += v; q += v * v;
      }
#pragma unroll
      for (int o = 1; o < 16; o <<= 1) {
        s += __shfl_xor(s, o);
        q += __shfl_xor(q, o);
      }
      if (lr == 0) {
        int row = wm + mi * 16 + (lk << 2) + j;
        red[row * 8 + (wid & 3) * 2] = s;
        red[row * 8 + (wid & 3) * 2 + 1] = q;
      }
    }
  }
  __syncthreads();
#pragma unroll
  for (int mi = 0; mi < 4; ++mi) {
#pragma unroll
    for (int j = 0; j < 4; ++j) {
      const int row = wm + mi * 16 + (lk << 2) + j;
      const size_t grow = (size_t)bm * 128 + row;
      float s = red[row * 8] + red[row * 8 + 2] + red[row * 8 + 4] + red[row * 8 + 6];
      float q = red[row * 8 + 1] + red[row * 8 + 3] + red[row * 8 + 5] + red[row * 8 + 7];
      float mu = s * (1.f / 256.f);
      float var = q * (1.f / 256.f) - mu * mu;
      float rstd = rsqrtf(var + 1e-5f);
#pragma unroll
      for (int ni = 0; ni < 4; ++ni) {
        int col = wn + ni * 16 + lr;
        float y = (acc[mi][ni][j] - mu) * rstd * wv[ni] + bv[ni];
        if (EPI == 0) {
          outb[grow * 256 + col] = f2bf(y);
        } else {
          float o = xres[grow * 256 + col] + y;
          outf[grow * 256 + col] = o;
          outb[grow * 256 + col] = f2bf(o);
        }
      }
    }
  }
}

// ---------------- KV partial reduction from bf16 kv buffer [row][512] = [K(elu)|V]
__global__ __launch_bounds__(256)
void kv_partial(const unsigned short* __restrict__ kvb, float* __restrict__ part) {
  const int ch = blockIdx.x, h = blockIdx.y, n = blockIdx.z;
  const int t = threadIdx.x, wave = t >> 6, lane = t & 63;
  __shared__ float kb[4][8][36];
  __shared__ float vb[4][8][36];
  const int dq = lane >> 3, vq = lane & 7;
  float a[4][4];
  float ks[4] = {0.f, 0.f, 0.f, 0.f};
#pragma unroll
  for (int i = 0; i < 4; ++i)
#pragma unroll
    for (int j = 0; j < 4; ++j) a[i][j] = 0.f;

  const int s_base = ch * 480 + wave * 120;
  const int half = lane >> 5, l = lane & 31, r = l >> 2, c8 = l & 3;
  const unsigned short* src = kvb + ((size_t)n * 4800 + s_base + r) * 512 +
                              half * 256 + h * 32 + c8 * 8;
  float* dst = (half ? &vb[wave][r][0] : &kb[wave][r][0]) + c8 * 8;

  for (int it = 0; it < 15; ++it) {
    __syncthreads();
    short8 raw = *(const short8*)(src + (size_t)it * 8 * 512);
#pragma unroll
    for (int e = 0; e < 8; ++e) dst[e] = bf2f((unsigned short)raw[e]);
    __syncthreads();
#pragma unroll
    for (int si = 0; si < 8; ++si) {
      float4 kq = *(const float4*)&kb[wave][si][dq * 4];
      float4 vv = *(const float4*)&vb[wave][si][vq * 4];
      ks[0] += kq.x; ks[1] += kq.y; ks[2] += kq.z; ks[3] += kq.w;
      a[0][0] += kq.x * vv.x; a[0][1] += kq.x * vv.y; a[0][2] += kq.x * vv.z; a[0][3] += kq.x * vv.w;
      a[1][0] += kq.y * vv.x; a[1][1] += kq.y * vv.y; a[1][2] += kq.y * vv.z; a[1][3] += kq.y * vv.w;
      a[2][0] += kq.z * vv.x; a[2][1] += kq.z * vv.y; a[2][2] += kq.z * vv.z; a[2][3] += kq.z * vv.w;
      a[3][0] += kq.w * vv.x; a[3][1] += kq.w * vv.y; a[3][2] += kq.w * vv.z; a[3][3] += kq.w * vv.w;
    }
  }
  float* pb = part + ((size_t)((n * 8 + h) * 40 + ch * 4 + wave)) * 1056;
#pragma unroll
  for (int i = 0; i < 4; ++i) {
#pragma unroll
    for (int j = 0; j < 4; ++j) pb[(dq * 4 + i) * 32 + vq * 4 + j] = a[i][j];
    if (vq == 0) pb[1024 + dq * 4 + i] = ks[i];
  }
}

// ---------------- reduce 40 partials; KV written bf16 in exact MFMA B-fragment order
__global__ __launch_bounds__(256)
void kv_reduce(const float* __restrict__ part, unsigned short* __restrict__ KVb,
               float* __restrict__ Ksum) {
  const int nh = blockIdx.x, t = threadIdx.x;
  const float* pb = part + (size_t)nh * 40 * 1056;
#pragma unroll
  for (int j = 0; j < 4; ++j) {
    int e = t * 4 + j;
    float s = 0.f;
    for (int c = 0; c < 40; ++c) s += pb[c * 1056 + e];
    int dd = e >> 5, vv = e & 31;
    size_t addr = ((size_t)(nh * 2 + (vv >> 4)) * 64 + ((dd >> 3) * 16 + (vv & 15))) * 8 + (dd & 7);
    KVb[addr] = f2bf(s);
  }
  if (t < 32) {
    float s = 0.f;
    for (int c = 0; c < 40; ++c) s += pb[c * 1056 + 1024 + t];
    Ksum[nh * 32 + t] = s;
  }
}

// ---------------- msg = (Q @ KV) * z, z = 1/(Q.Ksum + 1e-6); Q already elu'd, bf16
__global__ __launch_bounds__(256)
void msg_kernel(const unsigned short* __restrict__ qb, const unsigned short* __restrict__ KVb,
                const float* __restrict__ Ksum, unsigned short* __restrict__ msg) {
  const int n = blockIdx.y;
  const int wave = threadIdx.x >> 6, lane = threadIdx.x & 63;
  const int lr = lane & 15, lk = lane >> 4;
  const int lrow = blockIdx.x * 64 + wave * 16 + lr;
  const unsigned short* qrow = qb + ((size_t)n * 4800 + lrow) * 256;
  const short8* kvv = (const short8*)KVb;
  for (int h = 0; h < 8; ++h) {
    short8 af = *(const short8*)(qrow + h * 32 + lk * 8);
    const float* ksp = Ksum + (n * 8 + h) * 32 + lk * 8;
    float zp = 0.f;
#pragma unroll
    for (int j = 0; j < 8; ++j) zp += bf2f((unsigned short)af[j]) * ksp[j];
    zp += __shfl_xor(zp, 16);
    zp += __shfl_xor(zp, 32);
    float z = 1.f / (zp + 1e-6f);
    short8 b0 = kvv[((size_t)(n * 8 + h) * 2 + 0) * 64 + lane];
    short8 b1 = kvv[((size_t)(n * 8 + h) * 2 + 1) * 64 + lane];
    f32x4 acc0 = (f32x4){0.f, 0.f, 0.f, 0.f}, acc1 = (f32x4){0.f, 0.f, 0.f, 0.f};
    acc0 = __builtin_amdgcn_mfma_f32_16x16x32_bf16(af, b0, acc0, 0, 0, 0);
    acc1 = __builtin_amdgcn_mfma_f32_16x16x32_bf16(af, b1, acc1, 0, 0, 0);
#pragma unroll
    for (int j = 0; j < 4; ++j) {
      int rr = lk * 4 + j;
      float zj = __shfl(z, rr);
      int row = blockIdx.x * 64 + wave * 16 + rr;
      size_t base = ((size_t)n * 4800 + row) * 256 + h * 32;
      msg[base + lr] = f2bf(acc0[j] * zj);
      msg[base + 16 + lr] = f2bf(acc1[j] * zj);
    }
  }
}

extern "C" void kernel_launch(void* const* d_in, const int* in_sizes, int n_in,
                              void* d_out, int out_size, void* d_ws, size_t ws_size,
                              hipStream_t stream) {
  (void)in_sizes; (void)n_in; (void)out_size; (void)ws_size;
  const float* feat0 = (const float*)d_in[0];
  const float* feat1 = (const float*)d_in[1];
  const float* Wq = (const float*)d_in[2];
  const float* Wk = (const float*)d_in[3];
  const float* Wv = (const float*)d_in[4];
  const float* Wm = (const float*)d_in[5];
  const float* W1 = (const float*)d_in[6];
  const float* W2 = (const float*)d_in[7];
  const float* ln1w = (const float*)d_in[8];
  const float* ln1b = (const float*)d_in[9];
  const float* ln2w = (const float*)d_in[10];
  const float* ln2b = (const float*)d_in[11];

  float* F0 = (float*)d_out;
  float* F1 = F0 + (size_t)4915200;

  size_t off = 0;
  auto alloc = [&](size_t bytes) -> void* {
    void* p = (char*)d_ws + off;
    off += (bytes + 255) & ~(size_t)255;
    return p;
  };
  unsigned short* Fb     = (unsigned short*)alloc((size_t)38400 * 256 * 2);
  unsigned short* qb     = (unsigned short*)alloc((size_t)38400 * 256 * 2);
  unsigned short* kvb    = (unsigned short*)alloc((size_t)38400 * 512 * 2);  // also h1b
  unsigned short* msgb   = (unsigned short*)alloc((size_t)38400 * 256 * 2);
  unsigned short* msglnb = (unsigned short*)alloc((size_t)38400 * 256 * 2);
  float*          part   = (float*)alloc((size_t)64 * 40 * 1056 * 4);
  unsigned short* KVb    = (unsigned short*)alloc((size_t)65536 * 2);
  float*          Ksum   = (float*)alloc((size_t)2048 * 4);
  unsigned short* WqkvT  = (unsigned short*)alloc((size_t)8 * 196608 * 2);
  unsigned short* WmT    = (unsigned short*)alloc((size_t)8 * 65536 * 2);
  unsigned short* W1T    = (unsigned short*)alloc((size_t)8 * 262144 * 2);
  unsigned short* W2T    = (unsigned short*)alloc((size_t)8 * 131072 * 2);
  unsigned short* h1b = kvb;
  unsigned short* F0b = Fb;
  unsigned short* F1b = Fb + (size_t)19200 * 256;

  init_feat<<<4800, 256, 0, stream>>>(feat0, F0, F0b, 1228800);
  init_feat<<<4800, 256, 0, stream>>>(feat1, F1, F1b, 1228800);

  wprep<<<dim3(4, 4, 8), 256, 0, stream>>>(Wq, WqkvT, 256, 256, 196608);
  wprep<<<dim3(4, 4, 8), 256, 0, stream>>>(Wk, WqkvT + 65536, 256, 256, 196608);
  wprep<<<dim3(4, 4, 8), 256, 0, stream>>>(Wv, WqkvT + 131072, 256, 256, 196608);
  wprep<<<dim3(4, 4, 8), 256, 0, stream>>>(Wm, WmT, 256, 256, 65536);
  wprep<<<dim3(8, 8, 8), 256, 0, stream>>>(W1, W1T, 512, 512, 262144);
  wprep<<<dim3(4, 8, 8), 256, 0, stream>>>(W2, W2T, 512, 256, 131072);

  // ---- self pair, batched M=38400
  auto enc_self = [&](int i) {
    gemm_bt<4><<<1800, 256, 0, stream>>>(Fb, nullptr, WqkvT + (size_t)i * 196608,
                                         qb, kvb, 38400, 768, 256, 256);
    kv_partial<<<dim3(10, 8, 8), 256, 0, stream>>>(kvb, part);
    kv_reduce<<<64, 256, 0, stream>>>(part, KVb, Ksum);
    msg_kernel<<<dim3(75, 8), 256, 0, stream>>>(qb, KVb, Ksum, msgb);
    gemm_ln<0><<<300, 512, 0, stream>>>(msgb, WmT + (size_t)i * 65536,
                                        ln1w + i * 256, ln1b + i * 256,
                                        nullptr, nullptr, msglnb, 256);
    gemm_bt<1><<<1200, 256, 0, stream>>>(Fb, msglnb, W1T + (size_t)i * 262144,
                                         h1b, nullptr, 38400, 512, 512, 256);
    gemm_ln<1><<<300, 512, 0, stream>>>(h1b, W2T + (size_t)i * 131072,
                                        ln2w + i * 256, ln2b + i * 256,
                                        F0, F0, Fb, 512);
  };

  // ---- one cross enc (M=19200)
  auto enc_cross = [&](float* X, unsigned short* Xb, unsigned short* Sb, int i) {
    gemm_bt<3><<<300, 256, 0, stream>>>(Xb, nullptr, WqkvT + (size_t)i * 196608,
                                        qb, nullptr, 19200, 256, 256, 256);
    gemm_bt<2><<<600, 256, 0, stream>>>(Sb, nullptr, WqkvT + (size_t)i * 196608 + 65536,
                                        kvb, nullptr, 19200, 512, 256, 256);
    kv_partial<<<dim3(10, 8, 4), 256, 0, stream>>>(kvb, part);
    kv_reduce<<<32, 256, 0, stream>>>(part, KVb, Ksum);
    msg_kernel<<<dim3(75, 4), 256, 0, stream>>>(qb, KVb, Ksum, msgb);
    gemm_ln<0><<<150, 512, 0, stream>>>(msgb, WmT + (size_t)i * 65536,
                                        ln1w + i * 256, ln1b + i * 256,
                                        nullptr, nullptr, msglnb, 256);
    gemm_bt<1><<<600, 256, 0, stream>>>(Xb, msglnb, W1T + (size_t)i * 262144,
                                        h1b, nullptr, 19200, 512, 512, 256);
    gemm_ln<1><<<150, 512, 0, stream>>>(h1b, W2T + (size_t)i * 131072,
                                        ln2w + i * 256, ln2b + i * 256,
                                        X, X, Xb, 512);
  };

  for (int i = 0; i < 8; ++i) {
    if ((i & 1) == 0) {
      enc_self(i);
    } else {
      enc_cross(F0, F0b, F1b, i);
      enc_cross(F1, F1b, F0b, i);
    }
  }
}